// Round 1
// 1549.857 us; speedup vs baseline: 1.0953x; 1.0953x over previous
//
#include <hip/hip_runtime.h>

#define N_NODES 50000
#define N_EDGES 800000
#define HID 64
#define NLAYERS 4

#define K1PAD 224
#define TPITCH 72

typedef short bf16x8 __attribute__((ext_vector_type(8)));
typedef float f32x4 __attribute__((ext_vector_type(4)));

__device__ __forceinline__ unsigned short f2b(float f) {
  union { float f; unsigned int u; } v; v.f = f;
  unsigned int u = v.u;
  return (unsigned short)((u + 0x7fffu + ((u >> 16) & 1u)) >> 16);
}
__device__ __forceinline__ float b2f(unsigned short s) {
  union { unsigned int u; float f; } v; v.u = ((unsigned int)s) << 16;
  return v.f;
}
__device__ __forceinline__ float silu_f(float x) {
  return x / (1.0f + __expf(-x));
}

// ---------------- weight conversion ----------------
// eW1 [L,193,64] -> Wt1 [L,64,224] bf16, transposed + k-permuted:
// new k: 0..63 h_row, 64..127 h_col, 128..191 e, 192 radial, 193.. zero
__global__ void k_convW1(const float* __restrict__ eW1, unsigned short* __restrict__ Wt1) {
  int id = blockIdx.x * 256 + threadIdx.x;
  if (id >= NLAYERS * 64 * K1PAD) return;
  int k = id % K1PAD; int rem = id / K1PAD; int o = rem % 64; int l = rem / 64;
  int src = (k < 128) ? k : (k < 192 ? k + 1 : (k == 192 ? 128 : -1));
  float v = (src >= 0) ? eW1[((size_t)l * 193 + src) * 64 + o] : 0.0f;
  Wt1[id] = f2b(v);
}
// W [L,K,64] -> Wt [L,64,K] bf16
__global__ void k_convT(const float* __restrict__ W, unsigned short* __restrict__ Wt, int K) {
  int id = blockIdx.x * 256 + threadIdx.x;
  if (id >= NLAYERS * 64 * K) return;
  int k = id % K; int rem = id / K; int o = rem % 64; int l = rem / 64;
  Wt[id] = f2b(W[((size_t)l * K + k) * 64 + o]);
}

// ---------------- embeddings ----------------
__global__ void k_h0(const float* __restrict__ hin, const float* __restrict__ W,
                     const float* __restrict__ b, float* __restrict__ h,
                     unsigned short* __restrict__ hbf) {
  int id = blockIdx.x * 256 + threadIdx.x;
  if (id >= N_NODES * 64) return;
  int n = id >> 6, j = id & 63;
  float s = b[j];
#pragma unroll
  for (int k = 0; k < 16; k++) s += hin[n * 16 + k] * W[k * 64 + j];
  h[id] = s;
  hbf[id] = f2b(s);
}
__global__ void k_e0(const float* __restrict__ ea, const float* __restrict__ W,
                     const float* __restrict__ b, unsigned short* __restrict__ ebuf) {
  int id = blockIdx.x * 256 + threadIdx.x;
  if (id >= N_EDGES * 64) return;
  int e = id >> 6, j = id & 63;
  float s = b[j];
#pragma unroll
  for (int k = 0; k < 8; k++) s += ea[e * 8 + k] * W[k * 64 + j];
  ebuf[id] = f2b(s);
}

// ---------------- fused edge kernel (one layer) ----------------
// Barrier-free: every phase is wave-private (wave w owns edges w*16..w*16+15).
// A-fragments for GEMM1 load DIRECTLY from global bf16 (hbf/ebuf) — no LDS staging.
__global__ __launch_bounds__(256) void edge_kernel(
    const unsigned short* __restrict__ hbf, unsigned short* __restrict__ ebuf,
    const float* __restrict__ xin, float* __restrict__ xout,
    float* __restrict__ agg, const int* __restrict__ eidx,
    const float* __restrict__ emask,
    const unsigned short* __restrict__ Wt1,
    const unsigned short* __restrict__ Wt2,
    const unsigned short* __restrict__ Wtc,
    const float* __restrict__ eb1, const float* __restrict__ eb2,
    const float* __restrict__ cb1, const float* __restrict__ cw2) {
  __shared__ __attribute__((aligned(16))) unsigned short sT[64 * TPITCH];
  __shared__ __attribute__((aligned(16))) unsigned short sM[64 * TPITCH];
  __shared__ float sNdx[64 * 3];
  __shared__ float sMaskS[64];
  __shared__ int sRow[64];

  const int t = threadIdx.x;
  const int lane = t & 63, w = t >> 6;
  const int q = lane >> 4, li = lane & 15;
  const int erow = w * 16 + li;                 // this lane's MFMA row (wave-private)
  const int e = blockIdx.x * 64 + erow;

  // edge scalars: all 4 q-groups compute their row's radial redundantly
  // (each lane needs its own row's radial for the k=192 fragment); q==0 writes
  // the cross-lane-needed scalars to (wave-private) LDS.
  const int r = eidx[e], c = eidx[N_EDGES + e];
  float dx0 = xin[r * 3 + 0] - xin[c * 3 + 0];
  float dx1 = xin[r * 3 + 1] - xin[c * 3 + 1];
  float dx2 = xin[r * 3 + 2] - xin[c * 3 + 2];
  float rad = dx0 * dx0 + dx1 * dx1 + dx2 * dx2;
  if (q == 0) {
    float inv = 1.0f / (sqrtf(rad) + 1.0f);
    sRow[erow] = r;
    sMaskS[erow] = emask[e];
    sNdx[erow * 3 + 0] = dx0 * inv;
    sNdx[erow * 3 + 1] = dx1 * inv;
    sNdx[erow * 3 + 2] = dx2 * inv;
  }

  const unsigned short* hr = hbf + (size_t)r * 64;
  const unsigned short* hc = hbf + (size_t)c * 64;
  const unsigned short* ep = ebuf + (size_t)e * 64;

  f32x4 acc[4];
  const f32x4 zero4 = {0.f, 0.f, 0.f, 0.f};
#pragma unroll
  for (int ct = 0; ct < 4; ct++) acc[ct] = zero4;

  // GEMM1: K = [h_row(64) | h_col(64) | e(64) | radial | pad], direct global A-fragments
  {
    bf16x8 afs[7];
    afs[0] = *(const bf16x8*)(hr + q * 8);
    afs[1] = *(const bf16x8*)(hr + 32 + q * 8);
    afs[2] = *(const bf16x8*)(hc + q * 8);
    afs[3] = *(const bf16x8*)(hc + 32 + q * 8);
    afs[4] = *(const bf16x8*)(ep + q * 8);
    afs[5] = *(const bf16x8*)(ep + 32 + q * 8);
    bf16x8 a6 = {0, 0, 0, 0, 0, 0, 0, 0};
    if (q == 0) a6[0] = (short)f2b(rad);
    afs[6] = a6;
#pragma unroll
    for (int ks = 0; ks < 7; ks++) {
      int kb = ks * 32 + q * 8;
#pragma unroll
      for (int ct = 0; ct < 4; ct++) {
        bf16x8 bfr = *(const bf16x8*)(Wt1 + (size_t)(ct * 16 + li) * K1PAD + kb);
        acc[ct] = __builtin_amdgcn_mfma_f32_16x16x32_bf16(afs[ks], bfr, acc[ct], 0, 0, 0);
      }
    }
  }
#pragma unroll
  for (int ct = 0; ct < 4; ct++) {
    float bias = eb1[ct * 16 + li];
#pragma unroll
    for (int r2 = 0; r2 < 4; r2++) {
      int el = w * 16 + q * 4 + r2;
      sT[el * TPITCH + ct * 16 + li] = f2b(silu_f(acc[ct][r2] + bias));
    }
  }
  // wave-private sT: same-wave DS ops are in-order — no barrier needed

  // GEMM2 -> m
#pragma unroll
  for (int ct = 0; ct < 4; ct++) acc[ct] = zero4;
#pragma unroll
  for (int ks = 0; ks < 2; ks++) {
    int kb = ks * 32 + q * 8;
    bf16x8 af = *(const bf16x8*)(sT + erow * TPITCH + kb);
#pragma unroll
    for (int ct = 0; ct < 4; ct++) {
      bf16x8 bfr = *(const bf16x8*)(Wt2 + (size_t)(ct * 16 + li) * 64 + kb);
      acc[ct] = __builtin_amdgcn_mfma_f32_16x16x32_bf16(af, bfr, acc[ct], 0, 0, 0);
    }
  }
#pragma unroll
  for (int ct = 0; ct < 4; ct++) {
    float bias = eb2[ct * 16 + li];
#pragma unroll
    for (int r2 = 0; r2 < 4; r2++) {
      int el = w * 16 + q * 4 + r2;
      float v = silu_f(acc[ct][r2] + bias) * sMaskS[el];
      sM[el * TPITCH + ct * 16 + li] = f2b(v);
      atomicAdd(&agg[(size_t)sRow[el] * 64 + ct * 16 + li], v);
    }
  }

  // write m back to ebuf (becomes next layer's e) — wave-private rows
  {
    int el2 = t >> 2, part = t & 3;
    const uint4* src = (const uint4*)(sM + el2 * TPITCH + part * 16);
    uint4* dst = (uint4*)(ebuf + (size_t)(blockIdx.x * 64 + el2) * 64 + part * 16);
    dst[0] = src[0]; dst[1] = src[1];
  }

  // GEMM3: u = silu(m@cW1+cb1), p = u . cw2
#pragma unroll
  for (int ct = 0; ct < 4; ct++) acc[ct] = zero4;
#pragma unroll
  for (int ks = 0; ks < 2; ks++) {
    int kb = ks * 32 + q * 8;
    bf16x8 af = *(const bf16x8*)(sM + erow * TPITCH + kb);
#pragma unroll
    for (int ct = 0; ct < 4; ct++) {
      bf16x8 bfr = *(const bf16x8*)(Wtc + (size_t)(ct * 16 + li) * 64 + kb);
      acc[ct] = __builtin_amdgcn_mfma_f32_16x16x32_bf16(af, bfr, acc[ct], 0, 0, 0);
    }
  }
  float p[4] = {0.f, 0.f, 0.f, 0.f};
#pragma unroll
  for (int ct = 0; ct < 4; ct++) {
    float bias = cb1[ct * 16 + li];
    float wv = cw2[ct * 16 + li];
#pragma unroll
    for (int r2 = 0; r2 < 4; r2++) p[r2] += silu_f(acc[ct][r2] + bias) * wv;
  }
#pragma unroll
  for (int m = 1; m < 16; m <<= 1) {
#pragma unroll
    for (int r2 = 0; r2 < 4; r2++) p[r2] += __shfl_xor(p[r2], m, 64);
  }
  if (li < 3) {
#pragma unroll
    for (int r2 = 0; r2 < 4; r2++) {
      int el = w * 16 + q * 4 + r2;
      atomicAdd(&xout[(size_t)sRow[el] * 3 + li], sNdx[el * 3 + li] * p[r2]);
    }
  }
}

// ---------------- node kernel (one layer) ----------------
// Barrier-free: wave-private sT; A-fragments load directly from hbf (bf16) and agg (f32->bf16).
__global__ __launch_bounds__(256) void node_kernel(
    float* __restrict__ h, unsigned short* __restrict__ hbf,
    const float* __restrict__ agg,
    float* __restrict__ xout, const float* __restrict__ nmask,
    const unsigned short* __restrict__ Wtn1,
    const unsigned short* __restrict__ Wtn2,
    const float* __restrict__ nb1, const float* __restrict__ nb2) {
  __shared__ __attribute__((aligned(16))) unsigned short sT[64 * TPITCH];
  const int t = threadIdx.x;
  const int nb = blockIdx.x * 64;

  if (t < 192) {
    int n2 = nb + t / 3, c2 = t % 3;
    if (n2 < N_NODES) xout[(size_t)n2 * 3 + c2] *= nmask[n2];
  }

  const int lane = t & 63, w = t >> 6;
  const int q = lane >> 4, li = lane & 15;
  const int nrow = w * 16 + li;
  const int n = nb + nrow;
  const bool valid = (n < N_NODES);
  const f32x4 zero4 = {0.f, 0.f, 0.f, 0.f};

  f32x4 acc[4];
#pragma unroll
  for (int ct = 0; ct < 4; ct++) acc[ct] = zero4;

  // A = [h(64) | agg(64)]; h direct bf16, agg converted in-register
  {
    bf16x8 afs[4];
    const bf16x8 az = {0, 0, 0, 0, 0, 0, 0, 0};
    if (valid) {
      afs[0] = *(const bf16x8*)(hbf + (size_t)n * 64 + q * 8);
      afs[1] = *(const bf16x8*)(hbf + (size_t)n * 64 + 32 + q * 8);
      const float* ap = agg + (size_t)n * 64;
      bf16x8 a2, a3;
#pragma unroll
      for (int j = 0; j < 8; j++) {
        a2[j] = (short)f2b(ap[q * 8 + j]);
        a3[j] = (short)f2b(ap[32 + q * 8 + j]);
      }
      afs[2] = a2; afs[3] = a3;
    } else {
      afs[0] = az; afs[1] = az; afs[2] = az; afs[3] = az;
    }
#pragma unroll
    for (int ks = 0; ks < 4; ks++) {
      int kb = ks * 32 + q * 8;
#pragma unroll
      for (int ct = 0; ct < 4; ct++) {
        bf16x8 bfr = *(const bf16x8*)(Wtn1 + (size_t)(ct * 16 + li) * 128 + kb);
        acc[ct] = __builtin_amdgcn_mfma_f32_16x16x32_bf16(afs[ks], bfr, acc[ct], 0, 0, 0);
      }
    }
  }
#pragma unroll
  for (int ct = 0; ct < 4; ct++) {
    float bias = nb1[ct * 16 + li];
#pragma unroll
    for (int r2 = 0; r2 < 4; r2++) {
      int nl = w * 16 + q * 4 + r2;
      sT[nl * TPITCH + ct * 16 + li] = f2b(silu_f(acc[ct][r2] + bias));
    }
  }
  // wave-private sT — no barrier

#pragma unroll
  for (int ct = 0; ct < 4; ct++) acc[ct] = zero4;
#pragma unroll
  for (int ks = 0; ks < 2; ks++) {
    int kb = ks * 32 + q * 8;
    bf16x8 af = *(const bf16x8*)(sT + nrow * TPITCH + kb);
#pragma unroll
    for (int ct = 0; ct < 4; ct++) {
      bf16x8 bfr = *(const bf16x8*)(Wtn2 + (size_t)(ct * 16 + li) * 64 + kb);
      acc[ct] = __builtin_amdgcn_mfma_f32_16x16x32_bf16(af, bfr, acc[ct], 0, 0, 0);
    }
  }
#pragma unroll
  for (int ct = 0; ct < 4; ct++) {
    float bias = nb2[ct * 16 + li];
#pragma unroll
    for (int r2 = 0; r2 < 4; r2++) {
      int node = nb + w * 16 + q * 4 + r2;
      if (node < N_NODES) {
        float nm = nmask[node];
        size_t o = (size_t)node * 64 + ct * 16 + li;
        float hv = (h[o] + acc[ct][r2] + bias) * nm;
        h[o] = hv;
        hbf[o] = f2b(hv);
      }
    }
  }
}

// ---------------- output heads ----------------
__global__ void k_hout(const float* __restrict__ h, const float* __restrict__ W,
                       const float* __restrict__ b, const float* __restrict__ nmask,
                       float* __restrict__ out) {
  int id = blockIdx.x * 256 + threadIdx.x;
  if (id >= N_NODES * 16) return;
  int n = id >> 4, j = id & 15;
  float s = b[j];
#pragma unroll
  for (int k = 0; k < 64; k++) s += h[(size_t)n * 64 + k] * W[k * 16 + j];
  out[id] = s * nmask[n];
}
__global__ void k_eout(const unsigned short* __restrict__ ebuf, const float* __restrict__ W,
                       const float* __restrict__ b, const float* __restrict__ emask,
                       float* __restrict__ out) {
  int id = blockIdx.x * 256 + threadIdx.x;
  if (id >= N_EDGES * 8) return;
  int e = id >> 3, j = id & 7;
  float s = b[j];
#pragma unroll
  for (int k = 0; k < 64; k++) s += b2f(ebuf[(size_t)e * 64 + k]) * W[k * 8 + j];
  out[id] = s * emask[e];
}

extern "C" void kernel_launch(void* const* d_in, const int* in_sizes, int n_in,
                              void* d_out, int out_size, void* d_ws, size_t ws_size,
                              hipStream_t stream) {
  (void)in_sizes; (void)n_in; (void)out_size; (void)ws_size;
  const float* in_h   = (const float*)d_in[0];
  const float* in_x   = (const float*)d_in[1];
  const float* in_ea  = (const float*)d_in[2];
  const float* nmask  = (const float*)d_in[3];
  const float* emask  = (const float*)d_in[4];
  const float* Wn_in  = (const float*)d_in[5];
  const float* bn_in  = (const float*)d_in[6];
  const float* Wn_out = (const float*)d_in[7];
  const float* bn_out = (const float*)d_in[8];
  const float* We_in  = (const float*)d_in[9];
  const float* be_in  = (const float*)d_in[10];
  const float* We_out = (const float*)d_in[11];
  const float* be_out = (const float*)d_in[12];
  const float* eW1    = (const float*)d_in[13];
  const float* eb1    = (const float*)d_in[14];
  const float* eW2    = (const float*)d_in[15];
  const float* eb2    = (const float*)d_in[16];
  const float* nW1    = (const float*)d_in[17];
  const float* nb1    = (const float*)d_in[18];
  const float* nW2    = (const float*)d_in[19];
  const float* nb2    = (const float*)d_in[20];
  const float* cW1    = (const float*)d_in[21];
  const float* cb1    = (const float*)d_in[22];
  const float* cW2    = (const float*)d_in[23];
  const int*   eidx   = (const int*)d_in[24];

  char* ws = (char*)d_ws;
  size_t off = 0;
  auto alloc = [&](size_t bytes) {
    size_t o = off; off = (off + bytes + 255) & ~(size_t)255; return (void*)(ws + o);
  };
  float* h             = (float*)alloc((size_t)N_NODES * 64 * 4);
  unsigned short* hbf  = (unsigned short*)alloc((size_t)N_NODES * 64 * 2);
  unsigned short* ebuf = (unsigned short*)alloc((size_t)N_EDGES * 64 * 2);
  float* agg           = (float*)alloc((size_t)N_NODES * 64 * 4);
  float* xb0           = (float*)alloc((size_t)N_NODES * 3 * 4);
  float* xb1           = (float*)alloc((size_t)N_NODES * 3 * 4);
  unsigned short* Wt1  = (unsigned short*)alloc((size_t)NLAYERS * 64 * K1PAD * 2);
  unsigned short* Wt2  = (unsigned short*)alloc((size_t)NLAYERS * 64 * 64 * 2);
  unsigned short* Wtc  = (unsigned short*)alloc((size_t)NLAYERS * 64 * 64 * 2);
  unsigned short* Wtn1 = (unsigned short*)alloc((size_t)NLAYERS * 64 * 128 * 2);
  unsigned short* Wtn2 = (unsigned short*)alloc((size_t)NLAYERS * 64 * 64 * 2);

  k_convW1<<<(NLAYERS * 64 * K1PAD + 255) / 256, 256, 0, stream>>>(eW1, Wt1);
  k_convT<<<(NLAYERS * 64 * 64 + 255) / 256, 256, 0, stream>>>(eW2, Wt2, 64);
  k_convT<<<(NLAYERS * 64 * 64 + 255) / 256, 256, 0, stream>>>(cW1, Wtc, 64);
  k_convT<<<(NLAYERS * 64 * 128 + 255) / 256, 256, 0, stream>>>(nW1, Wtn1, 128);
  k_convT<<<(NLAYERS * 64 * 64 + 255) / 256, 256, 0, stream>>>(nW2, Wtn2, 64);

  k_h0<<<(N_NODES * 64 + 255) / 256, 256, 0, stream>>>(in_h, Wn_in, bn_in, h, hbf);
  k_e0<<<(N_EDGES * 64 + 255) / 256, 256, 0, stream>>>(in_ea, We_in, be_in, ebuf);
  hipMemcpyAsync(xb0, in_x, (size_t)N_NODES * 3 * 4, hipMemcpyDeviceToDevice, stream);

  for (int l = 0; l < NLAYERS; l++) {
    float* xi = (l & 1) ? xb1 : xb0;
    float* xo = (l & 1) ? xb0 : xb1;
    hipMemsetAsync(agg, 0, (size_t)N_NODES * 64 * 4, stream);
    hipMemcpyAsync(xo, xi, (size_t)N_NODES * 3 * 4, hipMemcpyDeviceToDevice, stream);
    edge_kernel<<<N_EDGES / 64, 256, 0, stream>>>(
        hbf, ebuf, xi, xo, agg, eidx, emask,
        Wt1 + (size_t)l * 64 * K1PAD, Wt2 + (size_t)l * 64 * 64, Wtc + (size_t)l * 64 * 64,
        eb1 + l * 64, eb2 + l * 64, cb1 + l * 64, cW2 + l * 64);
    node_kernel<<<(N_NODES + 63) / 64, 256, 0, stream>>>(
        h, hbf, agg, xo, nmask,
        Wtn1 + (size_t)l * 64 * 128, Wtn2 + (size_t)l * 64 * 64, nb1 + l * 64, nb2 + l * 64);
  }

  float* out = (float*)d_out;
  k_hout<<<(N_NODES * 16 + 255) / 256, 256, 0, stream>>>(h, Wn_out, bn_out, nmask, out);
  k_eout<<<(N_EDGES * 8 + 255) / 256, 256, 0, stream>>>(ebuf, We_out, be_out, emask,
                                                        out + 950000);
  hipMemcpyAsync(out + 800000, xb0, (size_t)N_NODES * 3 * 4, hipMemcpyDeviceToDevice, stream);
}